// Round 1
// baseline (833.905 us; speedup 1.0000x reference)
//
#include <hip/hip_runtime.h>

// Problem constants (match reference)
#define T_LEN 4096
#define B_SZ  64
#define C_CH  512
#define W_WORDS 256
#define C4 (C_CH / 4)               // 128 float4 per channel row
#define TOTAL4 (T_LEN * B_SZ * C4)  // 33,554,432 float4 elements

typedef float f4 __attribute__((ext_vector_type(4)));

// Kernel 1: per-batch cumsum of durations + scatter word index into a
// [B, T] int map in workspace. widmap[b*T + t] = word index j covering
// time t, or -1 where t >= total duration.
// Layout is [B][T] (NOT [T][B]) so both the -1 init and the scatter are
// contiguous per block: consecutive lanes -> consecutive ints.
__global__ void build_widmap_kernel(const int* __restrict__ dur,
                                    int* __restrict__ widmap) {
    const int b = blockIdx.x;       // batch
    const int j = threadIdx.x;      // word index, 256 threads == W_WORDS

    __shared__ int s[W_WORDS];
    const int d = dur[b * W_WORDS + j];
    s[j] = d;
    __syncthreads();

    // Hillis-Steele inclusive scan over 256 elements
    #pragma unroll
    for (int off = 1; off < W_WORDS; off <<= 1) {
        int v = (j >= off) ? s[j - off] : 0;
        __syncthreads();
        s[j] += v;
        __syncthreads();
    }
    const int cum = s[j];
    const int start = cum - d;

    int* __restrict__ col = widmap + b * T_LEN;

    // Init to -1 (coalesced: lane i writes col[t0+i])
    for (int t = j; t < T_LEN; t += W_WORDS)
        col[t] = -1;
    __syncthreads();

    // Scatter: word j owns times [start, start+d) — contiguous ints
    for (int k = 0; k < d && (start + k) < T_LEN; k++)
        col[start + k] = j;
}

// Kernel 2: out = x + pe[wid], one float4 per loop step, grid-stride.
// A 64-lane wave spans half a channel row of one (t,b): widmap load is a
// wave-uniform broadcast and the validity branch is wave-uniform.
// x/out are stream-once 512 MiB each -> nontemporal to avoid evicting the
// L2-resident pe (<=512 KiB) and widmap (1 MiB).
__global__ __launch_bounds__(256) void add_pe_kernel(
        const f4* __restrict__ x,
        const f4* __restrict__ pe,
        const int* __restrict__ widmap,
        f4* __restrict__ out) {
    const int stride = gridDim.x * blockDim.x;
    for (int idx = blockIdx.x * blockDim.x + threadIdx.x;
         idx < TOTAL4; idx += stride) {
        const int c4 = idx & (C4 - 1);
        const int tb = idx >> 7;            // = t*B + b  (log2(C4) = 7)

        f4 v = __builtin_nontemporal_load(x + idx);
        const int wid = widmap[(tb & (B_SZ - 1)) * T_LEN + (tb >> 6)];
        if (wid >= 0) {
            const f4 p = pe[wid * C4 + c4];
            v += p;
        }
        __builtin_nontemporal_store(v, out + idx);
    }
}

extern "C" void kernel_launch(void* const* d_in, const int* in_sizes, int n_in,
                              void* d_out, int out_size, void* d_ws, size_t ws_size,
                              hipStream_t stream) {
    const float* x   = (const float*)d_in[0];        // [T, B, C] fp32
    const float* pe  = (const float*)d_in[1];        // [MAX_LEN, C] fp32
    const int*   dur = (const int*)d_in[2];          // [B, W] int32
    // d_in[3] = train (static 1) — ignored

    float* out = (float*)d_out;                      // [T, B, C] fp32
    int*   widmap = (int*)d_ws;                      // [B, T] int32, 1 MiB

    // Kernel 1: tiny — builds the word-id map
    build_widmap_kernel<<<B_SZ, W_WORDS, 0, stream>>>(dur, widmap);

    // Kernel 2: the memory-bound add. 8192 blocks (32/CU) grid-stride,
    // 16 float4 per thread.
    const int threads = 256;
    const int blocks = 8192;
    add_pe_kernel<<<blocks, threads, 0, stream>>>(
        (const f4*)x, (const f4*)pe, widmap, (f4*)out);
}